// Round 11
// baseline (678.452 us; speedup 1.0000x reference)
//
#include <hip/hip_runtime.h>
#include <stdint.h>
#include <math.h>

// Problem constants
#define NN 8192     // graph nodes == GEMM K
#define HD 256      // hidden dim == GEMM N
#define BATCH 2048
#define KSPLIT 8
#define KCH (NN / KSPLIT)   // 1024 K per kblk
#define GREP 8              // DIAGNOSTIC: repeat GEMM body 8x inside the kernel
                            // so the dispatch exceeds the ~155us profiler floor
                            // and finally yields real per-kernel counters.

typedef __attribute__((ext_vector_type(8))) short bf16x8;
typedef __attribute__((ext_vector_type(4))) float f32x4;

static __device__ __forceinline__ uint32_t pack_bf2(float x, float y) {
  union { float f; uint32_t u; } a, b; a.f = x; b.f = y;
  uint32_t ua = a.u + 0x7FFFu + ((a.u >> 16) & 1u);
  uint32_t ub = b.u + 0x7FFFu + ((b.u >> 16) & 1u);
  return (ua >> 16) | (ub & 0xFFFF0000u);
}
static __device__ __forceinline__ float bf_lo(uint32_t u) {
  return __uint_as_float(u << 16);
}
static __device__ __forceinline__ float bf_hi(uint32_t u) {
  return __uint_as_float(u & 0xFFFF0000u);
}

// ---------------------------------------------------------------- prep:
// blocks 0..255:   emb[8192][256] f32 -> Bm frag-major bf16
// blocks 256..351: conv weights -> Wm frag-major bf16 (kc 0..15, ci 0..23)
extern "C" __global__ void k_prep(const float* __restrict__ emb,
                                  const float* __restrict__ k1,
                                  const float* __restrict__ k2,
                                  uint16_t* __restrict__ Bm,
                                  uint16_t* __restrict__ Wm) {
  const int tid = threadIdx.x;
  if (blockIdx.x < 256) {
    __shared__ float ts[32][257];
    const int kc = blockIdx.x;
#pragma unroll
    for (int i = 0; i < 32; i++)
      ts[i][tid] = emb[(size_t)(kc * 32 + i) * HD + tid];
    __syncthreads();
#pragma unroll
    for (int c = 0; c < 4; c++) {
      int e = c * 256 + tid;
      int ci = e >> 6, l = e & 63;
      int g = l >> 4, col = ci * 16 + (l & 15);
      uint4 v;
      v.x = pack_bf2(ts[g * 8 + 0][col], ts[g * 8 + 1][col]);
      v.y = pack_bf2(ts[g * 8 + 2][col], ts[g * 8 + 3][col]);
      v.z = pack_bf2(ts[g * 8 + 4][col], ts[g * 8 + 5][col]);
      v.w = pack_bf2(ts[g * 8 + 6][col], ts[g * 8 + 7][col]);
      ((uint4*)Bm)[(size_t)kc * 1024 + e] = v;
    }
  } else {
    const int c = (blockIdx.x - 256) * 256 + tid;   // 0..24575
    const int lcl = c & 63;
    const int ci = (c >> 6) % 24;
    const int kc = c / (24 * 64);
    const int j = ci * 16 + (lcl & 15);
    const int k0 = kc * 32 + ((lcl >> 4) << 3);
    float f[8];
#pragma unroll
    for (int jj = 0; jj < 8; jj++) {
      int k = k0 + jj;
      f[jj] = (j < 128) ? k1[j * 514 + 1 + k]
            : (j < 256) ? k2[(j - 128) * 1028 + 515 + k]
                        : k2[(j - 256) * 1028 + 1 + k];
    }
    uint4 v;
    v.x = pack_bf2(f[0], f[1]); v.y = pack_bf2(f[2], f[3]);
    v.z = pack_bf2(f[4], f[5]); v.w = pack_bf2(f[6], f[7]);
    *(uint4*)(Wm + (size_t)c * 8) = v;
  }
}

// ---------------------------------------------------------------- GEMM:
// r6 body, wrapped in a GREP-times repeat loop (identical work + stores each
// rep; result unchanged). BM=64, 4 waves, BK=64, grid 512 (2 blocks/CU).
extern "C" __global__ __launch_bounds__(256, 2)
void k_gemm(const float* __restrict__ A, const uint16_t* __restrict__ Bm,
            const int* __restrict__ bx, const int* __restrict__ by,
            uint16_t* __restrict__ Rp) {
  __shared__ __align__(16) uint16_t shb[16384];    // Af[2][4096] | Ct[64][256]
  const int tid = threadIdx.x;
  const int kblk = blockIdx.x & 7;                 // XCD = bid%8 == kblk
  const int mblk = blockIdx.x >> 3;
  const int wv = tid >> 6, l = tid & 63, g = l >> 4, l15 = l & 15;

  const int row = tid >> 2, q = tid & 3;
  const int gr = mblk * 64 + row;
  const int arow = (gr < BATCH) ? bx[gr] : by[gr - BATCH];
  const float* aSrc = A + (size_t)arow * NN + kblk * KCH + q * 4;
  int ldsO[4];
#pragma unroll
  for (int ii = 0; ii < 4; ii++) {
    int k0 = q * 4 + 16 * ii;
    int chunk = ((k0 >> 5) * 4 + (row >> 4)) * 64 + ((k0 >> 3) & 3) * 16 + (row & 15);
    ldsO[ii] = chunk * 16 + (k0 & 7) * 2;
  }
  const int ldsO0 = ldsO[0], ldsO1 = ldsO[1], ldsO2 = ldsO[2], ldsO3 = ldsO[3];
  const uint16_t* bWave = Bm + ((size_t)(kblk * 32 * 16 + wv * 4) * 64 + l) * 8;

  for (int rep = 0; rep < GREP; ++rep) {
    f32x4 acc[4][4] = {};
    float4 a0a, a0b, a0c, a0d, a1a, a1b, a1c, a1d, a2a, a2b, a2c, a2d;
    bf16x8 b0[2][4], b1[2][4];

#define ISSUE_A0(i) { const float* p_ = aSrc + (i) * 64; \
    a0a = *(const float4*)(p_);      a0b = *(const float4*)(p_ + 16); \
    a0c = *(const float4*)(p_ + 32); a0d = *(const float4*)(p_ + 48); }
#define ISSUE_A1(i) { const float* p_ = aSrc + (i) * 64; \
    a1a = *(const float4*)(p_);      a1b = *(const float4*)(p_ + 16); \
    a1c = *(const float4*)(p_ + 32); a1d = *(const float4*)(p_ + 48); }
#define ISSUE_A2(i) { const float* p_ = aSrc + (i) * 64; \
    a2a = *(const float4*)(p_);      a2b = *(const float4*)(p_ + 16); \
    a2c = *(const float4*)(p_ + 32); a2d = *(const float4*)(p_ + 48); }
#define ISSUE_B0(i) { \
    _Pragma("unroll") for (int kk = 0; kk < 2; kk++) \
    _Pragma("unroll") for (int cj = 0; cj < 4; cj++) \
      b0[kk][cj] = *(const bf16x8*)(bWave + ((i) * 2 + kk) * 8192 + cj * 512); }
#define ISSUE_B1(i) { \
    _Pragma("unroll") for (int kk = 0; kk < 2; kk++) \
    _Pragma("unroll") for (int cj = 0; cj < 4; cj++) \
      b1[kk][cj] = *(const bf16x8*)(bWave + ((i) * 2 + kk) * 8192 + cj * 512); }
#define PK1(va, off, buf) { uint2 v_; \
    v_.x = pack_bf2(va.x, va.y); v_.y = pack_bf2(va.z, va.w); \
    *(uint2*)((char*)shb + (buf) * 8192 + (off)) = v_; }
#define PACK_A0(buf) { PK1(a0a, ldsO0, buf); PK1(a0b, ldsO1, buf); \
                       PK1(a0c, ldsO2, buf); PK1(a0d, ldsO3, buf); }
#define PACK_A1(buf) { PK1(a1a, ldsO0, buf); PK1(a1b, ldsO1, buf); \
                       PK1(a1c, ldsO2, buf); PK1(a1d, ldsO3, buf); }
#define PACK_A2(buf) { PK1(a2a, ldsO0, buf); PK1(a2b, ldsO1, buf); \
                       PK1(a2c, ldsO2, buf); PK1(a2d, ldsO3, buf); }
#define COMPUTE(buf, bs) { \
    _Pragma("unroll") for (int kk = 0; kk < 2; kk++) { \
      _Pragma("unroll") for (int ri = 0; ri < 4; ri++) { \
        bf16x8 af = *(const bf16x8*)((char*)shb + (buf) * 8192 + \
                                     ((kk * 4 + ri) * 64 + l) * 16); \
        _Pragma("unroll") for (int cj = 0; cj < 4; cj++) \
          acc[ri][cj] = __builtin_amdgcn_mfma_f32_16x16x32_bf16( \
              af, bs[kk][cj], acc[ri][cj], 0, 0, 0); } } }
#define SYNC_ { asm volatile("s_waitcnt lgkmcnt(0)" ::: "memory"); \
    __builtin_amdgcn_s_barrier(); asm volatile("" ::: "memory"); }

    ISSUE_A0(0); ISSUE_A1(1); ISSUE_A2(2);
    ISSUE_B0(0); ISSUE_B1(1);
    PACK_A0(0);
    SYNC_;

#define SIX(base) \
  { COMPUTE(0, b0); ISSUE_A0((base) + 3); ISSUE_B0((base) + 2); PACK_A1(1); SYNC_; } \
  { COMPUTE(1, b1); ISSUE_A1((base) + 4); ISSUE_B1((base) + 3); PACK_A2(0); SYNC_; } \
  { COMPUTE(0, b0); ISSUE_A2((base) + 5); ISSUE_B0((base) + 4); PACK_A0(1); SYNC_; } \
  { COMPUTE(1, b1); ISSUE_A0((base) + 6); ISSUE_B1((base) + 5); PACK_A1(0); SYNC_; } \
  { COMPUTE(0, b0); ISSUE_A1((base) + 7); ISSUE_B0((base) + 6); PACK_A2(1); SYNC_; } \
  { COMPUTE(1, b1); ISSUE_A2((base) + 8); ISSUE_B1((base) + 7); PACK_A0(0); SYNC_; }

    SIX(0);
    SIX(6);
    { COMPUTE(0, b0); ISSUE_A0(15); ISSUE_B0(14); PACK_A1(1); SYNC_; }
    { COMPUTE(1, b1); ISSUE_B1(15); PACK_A2(0); SYNC_; }
    { COMPUTE(0, b0); PACK_A0(1); SYNC_; }
    { COMPUTE(1, b1); }
    SYNC_;                      // all LDS reads done; shb reusable as Ct

    uint16_t* Ct = shb;
#pragma unroll
    for (int ri = 0; ri < 4; ri++)
#pragma unroll
      for (int cj = 0; cj < 4; cj++)
#pragma unroll
        for (int r = 0; r < 4; r++) {
          float v = acc[ri][cj][r];
          float vn = __shfl_xor(v, 1);
          if ((l15 & 1) == 0) {
            int row16 = ri * 16 + g * 4 + r;
            int col = wv * 64 + cj * 16 + l15;
            *(uint32_t*)(Ct + row16 * 256 + col) = pack_bf2(v, vn);
          }
        }
    __syncthreads();
    {
      const int row2 = tid >> 2, cb = (tid & 3) * 64;
      const uint4* src = (const uint4*)(Ct + row2 * 256 + cb);
      uint16_t* dst = Rp + ((size_t)kblk * 4096 + mblk * 64 + row2) * HD + cb;
      uint4 v0 = src[0], v1 = src[1], v2 = src[2], v3 = src[3];
      ((uint4*)dst)[0] = v0; ((uint4*)dst)[1] = v1;
      ((uint4*)dst)[2] = v2; ((uint4*)dst)[3] = v3;
    }
    __syncthreads();            // Ct reads done before next rep's LDS writes
#undef ISSUE_A0
#undef ISSUE_A1
#undef ISSUE_A2
#undef ISSUE_B0
#undef ISSUE_B1
#undef PK1
#undef PACK_A0
#undef PACK_A1
#undef PACK_A2
#undef COMPUTE
#undef SYNC_
#undef SIX
  }
}

// ---------------------------------------------------------------- tail:
// 256 blocks x 8 batch rows (r6 verbatim).
extern "C" __global__ __launch_bounds__(256, 2)
void k_tail(const uint16_t* __restrict__ Rp, const uint16_t* __restrict__ Wm,
            const float* __restrict__ b1, const float* __restrict__ b2,
            const float* __restrict__ dw, const float* __restrict__ dbias,
            float* __restrict__ out) {
  __shared__ __align__(16) uint16_t t_frag[16 * 64 * 8];   // 16 KB
  __shared__ float Cl[8][388];
  __shared__ float coef[6][128];
  const int tid = threadIdx.x;
  const int b0 = blockIdx.x * 8;
  const int wv = tid >> 6, l = tid & 63, g = l >> 4, l15 = l & 15;
  if (tid < 128) {
    coef[0][tid] = dw[tid] + dw[256 + tid];
    coef[1][tid] = dw[128 + tid] + dw[384 + tid];
    coef[2][tid] = dw[512 + tid] + dw[768 + tid];
    coef[3][tid] = dw[640 + tid] + dw[896 + tid];
    coef[4][tid] = b1[tid];
    coef[5][tid] = b2[tid];
  }
  {
    const int r = tid >> 5, c8 = (tid & 31) * 8;
    float rq[8] = {}, ra[8] = {};
#pragma unroll
    for (int p = 0; p < KSPLIT; p++) {
      uint4 q4 = *(const uint4*)(Rp + ((size_t)p * 4096 + b0 + r) * HD + c8);
      uint4 a4 = *(const uint4*)(Rp + ((size_t)p * 4096 + BATCH + b0 + r) * HD + c8);
      const uint32_t* qw = (const uint32_t*)&q4;
      const uint32_t* aw = (const uint32_t*)&a4;
#pragma unroll
      for (int w = 0; w < 4; w++) {
        rq[2 * w] += bf_lo(qw[w]); rq[2 * w + 1] += bf_hi(qw[w]);
        ra[2 * w] += bf_lo(aw[w]); ra[2 * w + 1] += bf_hi(aw[w]);
      }
    }
    uint32_t tq[4], ml[4];
#pragma unroll
    for (int w = 0; w < 4; w++) {
      float d0 = rq[2 * w] - ra[2 * w], d1 = rq[2 * w + 1] - ra[2 * w + 1];
      tq[w] = pack_bf2(d0 * d0, d1 * d1);
      ml[w] = pack_bf2(rq[2 * w] * ra[2 * w], rq[2 * w + 1] * ra[2 * w + 1]);
    }
    const int kc1 = c8 >> 5, gm = (c8 >> 3) & 3;
    const int kc2 = 8 + kc1;
    *(uint4*)(t_frag + (kc1 * 64 + gm * 16 + r) * 8) = *(uint4*)tq;
    *(uint4*)(t_frag + (kc2 * 64 + gm * 16 + r) * 8) = *(uint4*)ml;
    uint4 z = {0, 0, 0, 0};
    *(uint4*)(t_frag + (kc1 * 64 + gm * 16 + 8 + r) * 8) = z;
    *(uint4*)(t_frag + (kc2 * 64 + gm * 16 + 8 + r) * 8) = z;
  }
  __syncthreads();
  {
    f32x4 acc[6] = {};
    const uint16_t* wB = Wm + ((size_t)(wv * 6) * 64 + l) * 8;
#pragma unroll 2
    for (int kc = 0; kc < 16; kc++) {
      bf16x8 af = *(const bf16x8*)(t_frag + (kc * 64 + l) * 8);
#pragma unroll
      for (int ci = 0; ci < 6; ci++) {
        bf16x8 w = *(const bf16x8*)(wB + (size_t)kc * 12288 + ci * 512);
        acc[ci] = __builtin_amdgcn_mfma_f32_16x16x32_bf16(af, w, acc[ci], 0, 0, 0);
      }
    }
#pragma unroll
    for (int ci = 0; ci < 6; ci++)
#pragma unroll
      for (int r = 0; r < 4; r++) {
        int row16 = g * 4 + r;
        if (row16 < 8) Cl[row16][wv * 96 + ci * 16 + l15] = acc[ci][r];
      }
  }
  __syncthreads();
  {
    const int r = tid >> 5, ch0 = (tid & 31) * 4;
    float s0 = 0.f, s1 = 0.f;
#pragma unroll
    for (int cc = 0; cc < 4; cc++) {
      const int c = ch0 + cc;
      float d1 = Cl[r][c], d2a = Cl[r][128 + c], d2b = Cl[r][256 + c];
      float bb1 = coef[4][c], bb2 = coef[5][c];
      float e1 = fmaxf(0.f, fmaxf(bb1, d1 + bb1));          // max-pool conv1
      float e2 = fmaxf(0.f, fmaxf(d2a + bb2, d2b + bb2));   // max-pool conv2
      s0 += e1 * coef[0][c] + e2 * coef[1][c];
      s1 += e1 * coef[2][c] + e2 * coef[3][c];
    }
#pragma unroll
    for (int off = 16; off >= 1; off >>= 1) {
      s0 += __shfl_xor(s0, off, 32);
      s1 += __shfl_xor(s1, off, 32);
    }
    if ((tid & 31) == 0) {
      s0 += dbias[0]; s1 += dbias[1];
      float m = fmaxf(s0, s1);
      float lse = m + logf(expf(s0 - m) + expf(s1 - m));
      out[(b0 + r) * 2] = s0 - lse;
      out[(b0 + r) * 2 + 1] = s1 - lse;
    }
  }
}

// ---------------------------------------------------------------- launch
extern "C" void kernel_launch(void* const* d_in, const int* in_sizes, int n_in,
                              void* d_out, int out_size, void* d_ws, size_t ws_size,
                              hipStream_t stream) {
  const float* emb = (const float*)d_in[0];
  const float* A   = (const float*)d_in[1];
  const float* k1  = (const float*)d_in[2];
  const float* b1  = (const float*)d_in[3];
  const float* k2  = (const float*)d_in[4];
  const float* b2  = (const float*)d_in[5];
  const float* dw  = (const float*)d_in[6];
  const float* dbi = (const float*)d_in[7];
  const int* bx = (const int*)d_in[8];
  const int* by = (const int*)d_in[9];
  float* out = (float*)d_out;
  char* ws = (char*)d_ws;
  // ws: [0,4M) Bm ; [4M,4.75M) Wm ; [8M,24M) Rp bf16
  uint16_t* Bm = (uint16_t*)ws;
  uint16_t* Wm = (uint16_t*)(ws + (4u << 20));
  uint16_t* Rp = (uint16_t*)(ws + (8u << 20));

  k_prep<<<352, 256, 0, stream>>>(emb, k1, k2, Bm, Wm);
  k_gemm<<<64 * KSPLIT, 256, 0, stream>>>(A, Bm, bx, by, Rp);
  k_tail<<<256, 256, 0, stream>>>(Rp, Wm, b1, b2, dw, dbi, out);
}

// Round 12
// 171.087 us; speedup vs baseline: 3.9655x; 3.9655x over previous
//
#include <hip/hip_runtime.h>
#include <stdint.h>
#include <math.h>

// Problem constants
#define NN 8192     // graph nodes == GEMM K
#define HD 256      // hidden dim == GEMM N
#define BATCH 2048
#define KSPLIT 16
#define KCH (NN / KSPLIT)   // 512 K per kblk -> 8 BK=64 steps

typedef __attribute__((ext_vector_type(8))) short bf16x8;
typedef __attribute__((ext_vector_type(4))) float f32x4;

static __device__ __forceinline__ uint32_t pack_bf2(float x, float y) {
  union { float f; uint32_t u; } a, b; a.f = x; b.f = y;
  uint32_t ua = a.u + 0x7FFFu + ((a.u >> 16) & 1u);
  uint32_t ub = b.u + 0x7FFFu + ((b.u >> 16) & 1u);
  return (ua >> 16) | (ub & 0xFFFF0000u);
}
static __device__ __forceinline__ float bf_lo(uint32_t u) {
  return __uint_as_float(u << 16);
}
static __device__ __forceinline__ float bf_hi(uint32_t u) {
  return __uint_as_float(u & 0xFFFF0000u);
}

// ---------------------------------------------------------------- prep:
// blocks 0..255:   emb[8192][256] f32 -> Bm frag-major bf16
// blocks 256..351: conv weights -> Wm frag-major bf16 (kc 0..15, ci 0..23)
extern "C" __global__ void k_prep(const float* __restrict__ emb,
                                  const float* __restrict__ k1,
                                  const float* __restrict__ k2,
                                  uint16_t* __restrict__ Bm,
                                  uint16_t* __restrict__ Wm) {
  const int tid = threadIdx.x;
  if (blockIdx.x < 256) {
    __shared__ float ts[32][257];
    const int kc = blockIdx.x;
#pragma unroll
    for (int i = 0; i < 32; i++)
      ts[i][tid] = emb[(size_t)(kc * 32 + i) * HD + tid];
    __syncthreads();
#pragma unroll
    for (int c = 0; c < 4; c++) {
      int e = c * 256 + tid;
      int ci = e >> 6, l = e & 63;
      int g = l >> 4, col = ci * 16 + (l & 15);
      uint4 v;
      v.x = pack_bf2(ts[g * 8 + 0][col], ts[g * 8 + 1][col]);
      v.y = pack_bf2(ts[g * 8 + 2][col], ts[g * 8 + 3][col]);
      v.z = pack_bf2(ts[g * 8 + 4][col], ts[g * 8 + 5][col]);
      v.w = pack_bf2(ts[g * 8 + 6][col], ts[g * 8 + 7][col]);
      ((uint4*)Bm)[(size_t)kc * 1024 + e] = v;
    }
  } else {
    const int c = (blockIdx.x - 256) * 256 + tid;   // 0..24575
    const int lcl = c & 63;
    const int ci = (c >> 6) % 24;
    const int kc = c / (24 * 64);
    const int j = ci * 16 + (lcl & 15);
    const int k0 = kc * 32 + ((lcl >> 4) << 3);
    float f[8];
#pragma unroll
    for (int jj = 0; jj < 8; jj++) {
      int k = k0 + jj;
      f[jj] = (j < 128) ? k1[j * 514 + 1 + k]
            : (j < 256) ? k2[(j - 128) * 1028 + 515 + k]
                        : k2[(j - 256) * 1028 + 1 + k];
    }
    uint4 v;
    v.x = pack_bf2(f[0], f[1]); v.y = pack_bf2(f[2], f[3]);
    v.z = pack_bf2(f[4], f[5]); v.w = pack_bf2(f[6], f[7]);
    *(uint4*)(Wm + (size_t)c * 8) = v;
  }
}

// ---------------------------------------------------------------- GEMM:
// BM=64, 4 waves (64 cols each), BK=64, KSPLIT=16 -> grid 1024 blocks,
// __launch_bounds__(256,4) => 4 blocks/CU, 16 waves/CU (2x TLP vs r6 —
// r11 counters showed latency-bound: all pipes <25% busy at 8 waves/CU).
// A f32 gathered coalesced -> regs -> bf16 frag-major LDS; B direct
// global->reg from frag-major Bm (XCD hosts kblk{x,x+8}: 512KB L2-resident).
extern "C" __global__ __launch_bounds__(256, 4)
void k_gemm(const float* __restrict__ A, const uint16_t* __restrict__ Bm,
            const int* __restrict__ bx, const int* __restrict__ by,
            uint16_t* __restrict__ Rp) {
  __shared__ __align__(16) uint16_t shb[16384];    // Af[2][4096] | Ct[64][256]
  const int tid = threadIdx.x;
  const int kblk = blockIdx.x & 15;                // bid%8 == kblk%8 == XCD
  const int mblk = blockIdx.x >> 4;
  const int wv = tid >> 6, l = tid & 63, g = l >> 4, l15 = l & 15;

  // A gather: row = tid>>2 (4 threads per row, 16B each, contiguous)
  const int row = tid >> 2, q = tid & 3;
  const int gr = mblk * 64 + row;
  const int arow = (gr < BATCH) ? bx[gr] : by[gr - BATCH];
  const float* aSrc = A + (size_t)arow * NN + kblk * KCH + q * 4;
  int ldsO[4];
#pragma unroll
  for (int ii = 0; ii < 4; ii++) {
    int k0 = q * 4 + 16 * ii;
    int chunk = ((k0 >> 5) * 4 + (row >> 4)) * 64 + ((k0 >> 3) & 3) * 16 + (row & 15);
    ldsO[ii] = chunk * 16 + (k0 & 7) * 2;
  }
  const int ldsO0 = ldsO[0], ldsO1 = ldsO[1], ldsO2 = ldsO[2], ldsO3 = ldsO[3];
  const uint16_t* bWave = Bm + (((size_t)kblk * (KCH / 32) * 16 + wv * 4) * 64 + l) * 8;

  f32x4 acc[4][4] = {};
  float4 a0a, a0b, a0c, a0d, a1a, a1b, a1c, a1d, a2a, a2b, a2c, a2d;
  bf16x8 b0[2][4], b1[2][4];

#define ISSUE_A0(i) { const float* p_ = aSrc + (i) * 64; \
    a0a = *(const float4*)(p_);      a0b = *(const float4*)(p_ + 16); \
    a0c = *(const float4*)(p_ + 32); a0d = *(const float4*)(p_ + 48); }
#define ISSUE_A1(i) { const float* p_ = aSrc + (i) * 64; \
    a1a = *(const float4*)(p_);      a1b = *(const float4*)(p_ + 16); \
    a1c = *(const float4*)(p_ + 32); a1d = *(const float4*)(p_ + 48); }
#define ISSUE_A2(i) { const float* p_ = aSrc + (i) * 64; \
    a2a = *(const float4*)(p_);      a2b = *(const float4*)(p_ + 16); \
    a2c = *(const float4*)(p_ + 32); a2d = *(const float4*)(p_ + 48); }
#define ISSUE_B0(i) { \
    _Pragma("unroll") for (int kk = 0; kk < 2; kk++) \
    _Pragma("unroll") for (int cj = 0; cj < 4; cj++) \
      b0[kk][cj] = *(const bf16x8*)(bWave + ((i) * 2 + kk) * 8192 + cj * 512); }
#define ISSUE_B1(i) { \
    _Pragma("unroll") for (int kk = 0; kk < 2; kk++) \
    _Pragma("unroll") for (int cj = 0; cj < 4; cj++) \
      b1[kk][cj] = *(const bf16x8*)(bWave + ((i) * 2 + kk) * 8192 + cj * 512); }
#define PK1(va, off, buf) { uint2 v_; \
    v_.x = pack_bf2(va.x, va.y); v_.y = pack_bf2(va.z, va.w); \
    *(uint2*)((char*)shb + (buf) * 8192 + (off)) = v_; }
#define PACK_A0(buf) { PK1(a0a, ldsO0, buf); PK1(a0b, ldsO1, buf); \
                       PK1(a0c, ldsO2, buf); PK1(a0d, ldsO3, buf); }
#define PACK_A1(buf) { PK1(a1a, ldsO0, buf); PK1(a1b, ldsO1, buf); \
                       PK1(a1c, ldsO2, buf); PK1(a1d, ldsO3, buf); }
#define PACK_A2(buf) { PK1(a2a, ldsO0, buf); PK1(a2b, ldsO1, buf); \
                       PK1(a2c, ldsO2, buf); PK1(a2d, ldsO3, buf); }
#define COMPUTE(buf, bs) { \
    _Pragma("unroll") for (int kk = 0; kk < 2; kk++) { \
      _Pragma("unroll") for (int ri = 0; ri < 4; ri++) { \
        bf16x8 af = *(const bf16x8*)((char*)shb + (buf) * 8192 + \
                                     ((kk * 4 + ri) * 64 + l) * 16); \
        _Pragma("unroll") for (int cj = 0; cj < 4; cj++) \
          acc[ri][cj] = __builtin_amdgcn_mfma_f32_16x16x32_bf16( \
              af, bs[kk][cj], acc[ri][cj], 0, 0, 0); } } }
#define SYNC_ { asm volatile("s_waitcnt lgkmcnt(0)" ::: "memory"); \
    __builtin_amdgcn_s_barrier(); asm volatile("" ::: "memory"); }

  // prologue: A 3-deep, B 2-deep
  ISSUE_A0(0); ISSUE_A1(1); ISSUE_A2(2);
  ISSUE_B0(0); ISSUE_B1(1);
  PACK_A0(0);
  SYNC_;
  // 8 steps (verified slot rotation; A-issues stop at i=7)
  { COMPUTE(0, b0); ISSUE_A0(3); ISSUE_B0(2); PACK_A1(1); SYNC_; }   // 0
  { COMPUTE(1, b1); ISSUE_A1(4); ISSUE_B1(3); PACK_A2(0); SYNC_; }   // 1
  { COMPUTE(0, b0); ISSUE_A2(5); ISSUE_B0(4); PACK_A0(1); SYNC_; }   // 2
  { COMPUTE(1, b1); ISSUE_A0(6); ISSUE_B1(5); PACK_A1(0); SYNC_; }   // 3
  { COMPUTE(0, b0); ISSUE_A1(7); ISSUE_B0(6); PACK_A2(1); SYNC_; }   // 4
  { COMPUTE(1, b1); ISSUE_B1(7); PACK_A0(0); SYNC_; }                // 5
  { COMPUTE(0, b0); PACK_A1(1); SYNC_; }                             // 6
  { COMPUTE(1, b1); }                                                // 7
  SYNC_;                      // all LDS reads done; shb reusable as Ct

  // epilogue: pack col-pairs, exchange via LDS, coalesced global stores
  uint16_t* Ct = shb;
#pragma unroll
  for (int ri = 0; ri < 4; ri++)
#pragma unroll
    for (int cj = 0; cj < 4; cj++)
#pragma unroll
      for (int r = 0; r < 4; r++) {
        float v = acc[ri][cj][r];
        float vn = __shfl_xor(v, 1);
        if ((l15 & 1) == 0) {
          int row16 = ri * 16 + g * 4 + r;
          int col = wv * 64 + cj * 16 + l15;
          *(uint32_t*)(Ct + row16 * 256 + col) = pack_bf2(v, vn);
        }
      }
  __syncthreads();
  {
    const int row2 = tid >> 2, cb = (tid & 3) * 64;
    const uint4* src = (const uint4*)(Ct + row2 * 256 + cb);
    uint16_t* dst = Rp + ((size_t)kblk * 4096 + mblk * 64 + row2) * HD + cb;
    uint4 v0 = src[0], v1 = src[1], v2 = src[2], v3 = src[3];
    ((uint4*)dst)[0] = v0; ((uint4*)dst)[1] = v1;
    ((uint4*)dst)[2] = v2; ((uint4*)dst)[3] = v3;
  }
#undef ISSUE_A0
#undef ISSUE_A1
#undef ISSUE_A2
#undef ISSUE_B0
#undef ISSUE_B1
#undef PK1
#undef PACK_A0
#undef PACK_A1
#undef PACK_A2
#undef COMPUTE
#undef SYNC_
}

// ---------------------------------------------------------------- tail:
// 256 blocks x 8 batch rows. Phase 1: reduce 16 Rp partials -> t (bf16 frag
// LDS). Phase 2: MFMA vs Wm. Fused max-pool/score/log-softmax.
extern "C" __global__ __launch_bounds__(256, 2)
void k_tail(const uint16_t* __restrict__ Rp, const uint16_t* __restrict__ Wm,
            const float* __restrict__ b1, const float* __restrict__ b2,
            const float* __restrict__ dw, const float* __restrict__ dbias,
            float* __restrict__ out) {
  __shared__ __align__(16) uint16_t t_frag[16 * 64 * 8];   // 16 KB
  __shared__ float Cl[8][388];
  __shared__ float coef[6][128];
  const int tid = threadIdx.x;
  const int b0 = blockIdx.x * 8;
  const int wv = tid >> 6, l = tid & 63, g = l >> 4, l15 = l & 15;
  if (tid < 128) {
    coef[0][tid] = dw[tid] + dw[256 + tid];
    coef[1][tid] = dw[128 + tid] + dw[384 + tid];
    coef[2][tid] = dw[512 + tid] + dw[768 + tid];
    coef[3][tid] = dw[640 + tid] + dw[896 + tid];
    coef[4][tid] = b1[tid];
    coef[5][tid] = b2[tid];
  }
  {
    const int r = tid >> 5, c8 = (tid & 31) * 8;
    float rq[8] = {}, ra[8] = {};
#pragma unroll
    for (int p = 0; p < KSPLIT; p++) {
      uint4 q4 = *(const uint4*)(Rp + ((size_t)p * 4096 + b0 + r) * HD + c8);
      uint4 a4 = *(const uint4*)(Rp + ((size_t)p * 4096 + BATCH + b0 + r) * HD + c8);
      const uint32_t* qw = (const uint32_t*)&q4;
      const uint32_t* aw = (const uint32_t*)&a4;
#pragma unroll
      for (int w = 0; w < 4; w++) {
        rq[2 * w] += bf_lo(qw[w]); rq[2 * w + 1] += bf_hi(qw[w]);
        ra[2 * w] += bf_lo(aw[w]); ra[2 * w + 1] += bf_hi(aw[w]);
      }
    }
    uint32_t tq[4], ml[4];
#pragma unroll
    for (int w = 0; w < 4; w++) {
      float d0 = rq[2 * w] - ra[2 * w], d1 = rq[2 * w + 1] - ra[2 * w + 1];
      tq[w] = pack_bf2(d0 * d0, d1 * d1);
      ml[w] = pack_bf2(rq[2 * w] * ra[2 * w], rq[2 * w + 1] * ra[2 * w + 1]);
    }
    const int kc1 = c8 >> 5, gm = (c8 >> 3) & 3;
    const int kc2 = 8 + kc1;
    *(uint4*)(t_frag + (kc1 * 64 + gm * 16 + r) * 8) = *(uint4*)tq;
    *(uint4*)(t_frag + (kc2 * 64 + gm * 16 + r) * 8) = *(uint4*)ml;
    uint4 z = {0, 0, 0, 0};
    *(uint4*)(t_frag + (kc1 * 64 + gm * 16 + 8 + r) * 8) = z;
    *(uint4*)(t_frag + (kc2 * 64 + gm * 16 + 8 + r) * 8) = z;
  }
  __syncthreads();
  {
    f32x4 acc[6] = {};
    const uint16_t* wB = Wm + ((size_t)(wv * 6) * 64 + l) * 8;
#pragma unroll 2
    for (int kc = 0; kc < 16; kc++) {
      bf16x8 af = *(const bf16x8*)(t_frag + (kc * 64 + l) * 8);
#pragma unroll
      for (int ci = 0; ci < 6; ci++) {
        bf16x8 w = *(const bf16x8*)(wB + (size_t)kc * 12288 + ci * 512);
        acc[ci] = __builtin_amdgcn_mfma_f32_16x16x32_bf16(af, w, acc[ci], 0, 0, 0);
      }
    }
#pragma unroll
    for (int ci = 0; ci < 6; ci++)
#pragma unroll
      for (int r = 0; r < 4; r++) {
        int row16 = g * 4 + r;
        if (row16 < 8) Cl[row16][wv * 96 + ci * 16 + l15] = acc[ci][r];
      }
  }
  __syncthreads();
  {
    const int r = tid >> 5, ch0 = (tid & 31) * 4;
    float s0 = 0.f, s1 = 0.f;
#pragma unroll
    for (int cc = 0; cc < 4; cc++) {
      const int c = ch0 + cc;
      float d1 = Cl[r][c], d2a = Cl[r][128 + c], d2b = Cl[r][256 + c];
      float bb1 = coef[4][c], bb2 = coef[5][c];
      float e1 = fmaxf(0.f, fmaxf(bb1, d1 + bb1));          // max-pool conv1
      float e2 = fmaxf(0.f, fmaxf(d2a + bb2, d2b + bb2));   // max-pool conv2
      s0 += e1 * coef[0][c] + e2 * coef[1][c];
      s1 += e1 * coef[2][c] + e2 * coef[3][c];
    }
#pragma unroll
    for (int off = 16; off >= 1; off >>= 1) {
      s0 += __shfl_xor(s0, off, 32);
      s1 += __shfl_xor(s1, off, 32);
    }
    if ((tid & 31) == 0) {
      s0 += dbias[0]; s1 += dbias[1];
      float m = fmaxf(s0, s1);
      float lse = m + logf(expf(s0 - m) + expf(s1 - m));
      out[(b0 + r) * 2] = s0 - lse;
      out[(b0 + r) * 2 + 1] = s1 - lse;
    }
  }
}

// ---------------------------------------------------------------- launch
extern "C" void kernel_launch(void* const* d_in, const int* in_sizes, int n_in,
                              void* d_out, int out_size, void* d_ws, size_t ws_size,
                              hipStream_t stream) {
  const float* emb = (const float*)d_in[0];
  const float* A   = (const float*)d_in[1];
  const float* k1  = (const float*)d_in[2];
  const float* b1  = (const float*)d_in[3];
  const float* k2  = (const float*)d_in[4];
  const float* b2  = (const float*)d_in[5];
  const float* dw  = (const float*)d_in[6];
  const float* dbi = (const float*)d_in[7];
  const int* bx = (const int*)d_in[8];
  const int* by = (const int*)d_in[9];
  float* out = (float*)d_out;
  char* ws = (char*)d_ws;
  // ws: [0,4M) Bm ; [4M,4.75M) Wm ; [8M,40M) Rp bf16 (KSPLIT=16)
  uint16_t* Bm = (uint16_t*)ws;
  uint16_t* Wm = (uint16_t*)(ws + (4u << 20));
  uint16_t* Rp = (uint16_t*)(ws + (8u << 20));

  k_prep<<<352, 256, 0, stream>>>(emb, k1, k2, Bm, Wm);
  k_gemm<<<64 * KSPLIT, 256, 0, stream>>>(A, Bm, bx, by, Rp);
  k_tail<<<256, 256, 0, stream>>>(Rp, Wm, b1, b2, dw, dbi, out);
}

// Round 13
// 72.272 us; speedup vs baseline: 9.3875x; 2.3673x over previous
//
#include <hip/hip_runtime.h>
#include <stdint.h>
#include <math.h>

// Problem constants
#define NN 8192     // graph nodes == GEMM K
#define HD 256      // hidden dim == GEMM N
#define BATCH 2048
#define KSPLIT 16
#define KCH (NN / KSPLIT)   // 512 K (floats) per kblk

typedef __attribute__((ext_vector_type(8))) short bf16x8;
typedef __attribute__((ext_vector_type(4))) float f32x4;

static __device__ __forceinline__ uint32_t pack_bf2(float x, float y) {
  union { float f; uint32_t u; } a, b; a.f = x; b.f = y;
  uint32_t ua = a.u + 0x7FFFu + ((a.u >> 16) & 1u);
  uint32_t ub = b.u + 0x7FFFu + ((b.u >> 16) & 1u);
  return (ua >> 16) | (ub & 0xFFFF0000u);
}
static __device__ __forceinline__ float bf_lo(uint32_t u) {
  return __uint_as_float(u << 16);
}
static __device__ __forceinline__ float bf_hi(uint32_t u) {
  return __uint_as_float(u & 0xFFFF0000u);
}

// ---------------------------------------------------------------- prep:
// blocks 0..255:   emb[8192][256] f32 -> Bm frag-major bf16
// blocks 256..351: conv weights -> Wm frag-major bf16 (kc 0..15, ci 0..23)
extern "C" __global__ void k_prep(const float* __restrict__ emb,
                                  const float* __restrict__ k1,
                                  const float* __restrict__ k2,
                                  uint16_t* __restrict__ Bm,
                                  uint16_t* __restrict__ Wm) {
  const int tid = threadIdx.x;
  if (blockIdx.x < 256) {
    __shared__ float ts[32][257];
    const int kc = blockIdx.x;
#pragma unroll
    for (int i = 0; i < 32; i++)
      ts[i][tid] = emb[(size_t)(kc * 32 + i) * HD + tid];
    __syncthreads();
#pragma unroll
    for (int c = 0; c < 4; c++) {
      int e = c * 256 + tid;
      int ci = e >> 6, l = e & 63;
      int g = l >> 4, col = ci * 16 + (l & 15);
      uint4 v;
      v.x = pack_bf2(ts[g * 8 + 0][col], ts[g * 8 + 1][col]);
      v.y = pack_bf2(ts[g * 8 + 2][col], ts[g * 8 + 3][col]);
      v.z = pack_bf2(ts[g * 8 + 4][col], ts[g * 8 + 5][col]);
      v.w = pack_bf2(ts[g * 8 + 6][col], ts[g * 8 + 7][col]);
      ((uint4*)Bm)[(size_t)kc * 1024 + e] = v;
    }
  } else {
    const int c = (blockIdx.x - 256) * 256 + tid;   // 0..24575
    const int lcl = c & 63;
    const int ci = (c >> 6) % 24;
    const int kc = c / (24 * 64);
    const int j = ci * 16 + (lcl & 15);
    const int k0 = kc * 32 + ((lcl >> 4) << 3);
    float f[8];
#pragma unroll
    for (int jj = 0; jj < 8; jj++) {
      int k = k0 + jj;
      f[jj] = (j < 128) ? k1[j * 514 + 1 + k]
            : (j < 256) ? k2[(j - 128) * 1028 + 515 + k]
                        : k2[(j - 256) * 1028 + 1 + k];
    }
    uint4 v;
    v.x = pack_bf2(f[0], f[1]); v.y = pack_bf2(f[2], f[3]);
    v.z = pack_bf2(f[4], f[5]); v.w = pack_bf2(f[6], f[7]);
    *(uint4*)(Wm + (size_t)c * 8) = v;
  }
}

// ---------------------------------------------------------------- GEMM:
// BM=64, KSPLIT=16, grid 1024, 2 blocks/CU. ONE-SHOT A staging: block bursts
// its whole 64x512 f32 A-chunk (2KB contiguous per row, unthrottled -> DRAM
// page-friendly; r11/r12 showed the barrier-paced 256B-trickle ran HBM at
// only 1.6 TB/s) into 64KB frag-major bf16 LDS. Then a ZERO-BARRIER K-loop:
// ds_read A-frags + wave-private B (L2-resident) + MFMA, compiler-pipelined.
extern "C" __global__ __launch_bounds__(256, 2)
void k_gemm(const float* __restrict__ A, const uint16_t* __restrict__ Bm,
            const int* __restrict__ bx, const int* __restrict__ by,
            uint16_t* __restrict__ Rp) {
  __shared__ __align__(16) uint16_t Asm[64 * 512];   // 64KB; reused as Ct
  const int tid = threadIdx.x;
  const int kblk = blockIdx.x & 15;                  // bid&7 == kblk&7 == XCD
  const int mblk = blockIdx.x >> 4;
  const int wv = tid >> 6, l = tid & 63, g = l >> 4, l15 = l & 15;

  // ---- phase 1: one-shot A staging ----
  // thread: row r = tid>>2, sub b = tid&3. instr m: float4 at row r,
  // floats m*16 + b*4  (per instr: 16 rows x 64B contiguous; per row the 32
  // instrs sweep 2KB sequentially -> deep bursts).
  {
    const int r = tid >> 2, b = tid & 3;
    const int gr = mblk * 64 + r;
    const int arow = (gr < BATCH) ? bx[gr] : by[gr - BATCH];
    const float* aSrc = A + (size_t)arow * NN + (size_t)kblk * KCH + b * 4;
    const int ris = r >> 4, l15s = r & 15;
    const int joff = (b & 1) << 2;                 // j8 = (b&1)*4
    const int gb = b >> 1;
#pragma unroll
    for (int half = 0; half < 2; ++half) {
      float4 t[16];
#pragma unroll
      for (int m16 = 0; m16 < 16; ++m16)
        t[m16] = *(const float4*)(aSrc + (half * 16 + m16) * 16);
#pragma unroll
      for (int m16 = 0; m16 < 16; ++m16) {
        const int m = half * 16 + m16;
        const int kc = m >> 1;
        const int gg = ((m & 1) << 1) + gb;
        const int off = ((kc * 4 + ris) * 64 + gg * 16 + l15s) * 8 + joff;
        uint2 v;
        v.x = pack_bf2(t[m16].x, t[m16].y);
        v.y = pack_bf2(t[m16].z, t[m16].w);
        *(uint2*)(Asm + off) = v;
      }
    }
  }
  __syncthreads();                                 // barrier #1 (only one!)

  // ---- phase 2: barrier-free K-loop ----
  // wave wv owns cols wv*64..+63 (ci = wv*4+cj). B chunk (kcg, ci) at
  // Bm[((kcg*16+ci)*64+l)*8], kcg = kblk*16 + kc.
  f32x4 acc[4][4] = {};
  const uint16_t* bWave = Bm + (((size_t)(kblk * 16) * 16 + wv * 4) * 64 + l) * 8;
#pragma unroll 4
  for (int kc = 0; kc < 16; ++kc) {
    bf16x8 bfr[4];
#pragma unroll
    for (int cj = 0; cj < 4; ++cj)
      bfr[cj] = *(const bf16x8*)(bWave + ((size_t)kc * 16 + cj) * 512);
    bf16x8 af[4];
#pragma unroll
    for (int ri = 0; ri < 4; ++ri)
      af[ri] = *(const bf16x8*)(Asm + (size_t)((kc * 4 + ri) * 64 + l) * 8);
#pragma unroll
    for (int ri = 0; ri < 4; ++ri)
#pragma unroll
      for (int cj = 0; cj < 4; ++cj)
        acc[ri][cj] = __builtin_amdgcn_mfma_f32_16x16x32_bf16(
            af[ri], bfr[cj], acc[ri][cj], 0, 0, 0);
  }
  __syncthreads();                                 // barrier #2: Asm -> Ct

  // ---- epilogue: pack col-pairs, LDS exchange, coalesced stores ----
  uint16_t* Ct = Asm;                              // 64 x 256 bf16 = 32KB
#pragma unroll
  for (int ri = 0; ri < 4; ri++)
#pragma unroll
    for (int cj = 0; cj < 4; cj++)
#pragma unroll
      for (int r = 0; r < 4; r++) {
        float v = acc[ri][cj][r];
        float vn = __shfl_xor(v, 1);
        if ((l15 & 1) == 0) {
          int row16 = ri * 16 + g * 4 + r;
          int col = wv * 64 + cj * 16 + l15;
          *(uint32_t*)(Ct + row16 * 256 + col) = pack_bf2(v, vn);
        }
      }
  __syncthreads();                                 // barrier #3
  {
    const int row2 = tid >> 2, cb = (tid & 3) * 64;
    const uint4* src = (const uint4*)(Ct + row2 * 256 + cb);
    uint16_t* dst = Rp + ((size_t)kblk * 4096 + mblk * 64 + row2) * HD + cb;
    uint4 v0 = src[0], v1 = src[1], v2 = src[2], v3 = src[3];
    ((uint4*)dst)[0] = v0; ((uint4*)dst)[1] = v1;
    ((uint4*)dst)[2] = v2; ((uint4*)dst)[3] = v3;
  }
}

// ---------------------------------------------------------------- tail:
// 256 blocks x 8 batch rows. Phase 1: reduce 16 Rp partials -> t (bf16 frag
// LDS). Phase 2: MFMA vs Wm. Fused max-pool/score/log-softmax.
extern "C" __global__ __launch_bounds__(256, 2)
void k_tail(const uint16_t* __restrict__ Rp, const uint16_t* __restrict__ Wm,
            const float* __restrict__ b1, const float* __restrict__ b2,
            const float* __restrict__ dw, const float* __restrict__ dbias,
            float* __restrict__ out) {
  __shared__ __align__(16) uint16_t t_frag[16 * 64 * 8];   // 16 KB
  __shared__ float Cl[8][388];
  __shared__ float coef[6][128];
  const int tid = threadIdx.x;
  const int b0 = blockIdx.x * 8;
  const int wv = tid >> 6, l = tid & 63, g = l >> 4, l15 = l & 15;
  if (tid < 128) {
    coef[0][tid] = dw[tid] + dw[256 + tid];
    coef[1][tid] = dw[128 + tid] + dw[384 + tid];
    coef[2][tid] = dw[512 + tid] + dw[768 + tid];
    coef[3][tid] = dw[640 + tid] + dw[896 + tid];
    coef[4][tid] = b1[tid];
    coef[5][tid] = b2[tid];
  }
  {
    const int r = tid >> 5, c8 = (tid & 31) * 8;
    float rq[8] = {}, ra[8] = {};
#pragma unroll
    for (int p = 0; p < KSPLIT; p++) {
      uint4 q4 = *(const uint4*)(Rp + ((size_t)p * 4096 + b0 + r) * HD + c8);
      uint4 a4 = *(const uint4*)(Rp + ((size_t)p * 4096 + BATCH + b0 + r) * HD + c8);
      const uint32_t* qw = (const uint32_t*)&q4;
      const uint32_t* aw = (const uint32_t*)&a4;
#pragma unroll
      for (int w = 0; w < 4; w++) {
        rq[2 * w] += bf_lo(qw[w]); rq[2 * w + 1] += bf_hi(qw[w]);
        ra[2 * w] += bf_lo(aw[w]); ra[2 * w + 1] += bf_hi(aw[w]);
      }
    }
    uint32_t tq[4], ml[4];
#pragma unroll
    for (int w = 0; w < 4; w++) {
      float d0 = rq[2 * w] - ra[2 * w], d1 = rq[2 * w + 1] - ra[2 * w + 1];
      tq[w] = pack_bf2(d0 * d0, d1 * d1);
      ml[w] = pack_bf2(rq[2 * w] * ra[2 * w], rq[2 * w + 1] * ra[2 * w + 1]);
    }
    const int kc1 = c8 >> 5, gm = (c8 >> 3) & 3;
    const int kc2 = 8 + kc1;
    *(uint4*)(t_frag + (kc1 * 64 + gm * 16 + r) * 8) = *(uint4*)tq;
    *(uint4*)(t_frag + (kc2 * 64 + gm * 16 + r) * 8) = *(uint4*)ml;
    uint4 z = {0, 0, 0, 0};
    *(uint4*)(t_frag + (kc1 * 64 + gm * 16 + 8 + r) * 8) = z;
    *(uint4*)(t_frag + (kc2 * 64 + gm * 16 + 8 + r) * 8) = z;
  }
  __syncthreads();
  {
    f32x4 acc[6] = {};
    const uint16_t* wB = Wm + ((size_t)(wv * 6) * 64 + l) * 8;
#pragma unroll 2
    for (int kc = 0; kc < 16; kc++) {
      bf16x8 af = *(const bf16x8*)(t_frag + (kc * 64 + l) * 8);
#pragma unroll
      for (int ci = 0; ci < 6; ci++) {
        bf16x8 w = *(const bf16x8*)(wB + (size_t)kc * 12288 + ci * 512);
        acc[ci] = __builtin_amdgcn_mfma_f32_16x16x32_bf16(af, w, acc[ci], 0, 0, 0);
      }
    }
#pragma unroll
    for (int ci = 0; ci < 6; ci++)
#pragma unroll
      for (int r = 0; r < 4; r++) {
        int row16 = g * 4 + r;
        if (row16 < 8) Cl[row16][wv * 96 + ci * 16 + l15] = acc[ci][r];
      }
  }
  __syncthreads();
  {
    const int r = tid >> 5, ch0 = (tid & 31) * 4;
    float s0 = 0.f, s1 = 0.f;
#pragma unroll
    for (int cc = 0; cc < 4; cc++) {
      const int c = ch0 + cc;
      float d1 = Cl[r][c], d2a = Cl[r][128 + c], d2b = Cl[r][256 + c];
      float bb1 = coef[4][c], bb2 = coef[5][c];
      float e1 = fmaxf(0.f, fmaxf(bb1, d1 + bb1));          // max-pool conv1
      float e2 = fmaxf(0.f, fmaxf(d2a + bb2, d2b + bb2));   // max-pool conv2
      s0 += e1 * coef[0][c] + e2 * coef[1][c];
      s1 += e1 * coef[2][c] + e2 * coef[3][c];
    }
#pragma unroll
    for (int off = 16; off >= 1; off >>= 1) {
      s0 += __shfl_xor(s0, off, 32);
      s1 += __shfl_xor(s1, off, 32);
    }
    if ((tid & 31) == 0) {
      s0 += dbias[0]; s1 += dbias[1];
      float m = fmaxf(s0, s1);
      float lse = m + logf(expf(s0 - m) + expf(s1 - m));
      out[(b0 + r) * 2] = s0 - lse;
      out[(b0 + r) * 2 + 1] = s1 - lse;
    }
  }
}

// ---------------------------------------------------------------- launch
extern "C" void kernel_launch(void* const* d_in, const int* in_sizes, int n_in,
                              void* d_out, int out_size, void* d_ws, size_t ws_size,
                              hipStream_t stream) {
  const float* emb = (const float*)d_in[0];
  const float* A   = (const float*)d_in[1];
  const float* k1  = (const float*)d_in[2];
  const float* b1  = (const float*)d_in[3];
  const float* k2  = (const float*)d_in[4];
  const float* b2  = (const float*)d_in[5];
  const float* dw  = (const float*)d_in[6];
  const float* dbi = (const float*)d_in[7];
  const int* bx = (const int*)d_in[8];
  const int* by = (const int*)d_in[9];
  float* out = (float*)d_out;
  char* ws = (char*)d_ws;
  // ws: [0,4M) Bm ; [4M,4.75M) Wm ; [8M,40M) Rp bf16 (KSPLIT=16)
  uint16_t* Bm = (uint16_t*)ws;
  uint16_t* Wm = (uint16_t*)(ws + (4u << 20));
  uint16_t* Rp = (uint16_t*)(ws + (8u << 20));

  k_prep<<<352, 256, 0, stream>>>(emb, k1, k2, Bm, Wm);
  k_gemm<<<64 * KSPLIT, 256, 0, stream>>>(A, Bm, bx, by, Rp);
  k_tail<<<256, 256, 0, stream>>>(Rp, Wm, b1, b2, dw, dbi, out);
}

// Round 14
// 61.233 us; speedup vs baseline: 11.0799x; 1.1803x over previous
//
#include <hip/hip_runtime.h>
#include <stdint.h>
#include <math.h>

// Problem constants
#define NN 8192     // graph nodes == GEMM K
#define HD 256      // hidden dim == GEMM N
#define BATCH 2048
#define KSPLIT 8
#define KCH (NN / KSPLIT)   // 1024 K (floats) per kblk -> 2 stages of 512

typedef __attribute__((ext_vector_type(8))) short bf16x8;
typedef __attribute__((ext_vector_type(4))) float f32x4;

static __device__ __forceinline__ uint32_t pack_bf2(float x, float y) {
  union { float f; uint32_t u; } a, b; a.f = x; b.f = y;
  uint32_t ua = a.u + 0x7FFFu + ((a.u >> 16) & 1u);
  uint32_t ub = b.u + 0x7FFFu + ((b.u >> 16) & 1u);
  return (ua >> 16) | (ub & 0xFFFF0000u);
}
static __device__ __forceinline__ float bf_lo(uint32_t u) {
  return __uint_as_float(u << 16);
}
static __device__ __forceinline__ float bf_hi(uint32_t u) {
  return __uint_as_float(u & 0xFFFF0000u);
}

// ---------------------------------------------------------------- prep:
// blocks 0..255:   emb[8192][256] f32 -> Bm frag-major bf16
// blocks 256..351: conv weights -> Wm frag-major bf16 (kc 0..15, ci 0..23)
extern "C" __global__ void k_prep(const float* __restrict__ emb,
                                  const float* __restrict__ k1,
                                  const float* __restrict__ k2,
                                  uint16_t* __restrict__ Bm,
                                  uint16_t* __restrict__ Wm) {
  const int tid = threadIdx.x;
  if (blockIdx.x < 256) {
    __shared__ float ts[32][257];
    const int kc = blockIdx.x;
#pragma unroll
    for (int i = 0; i < 32; i++)
      ts[i][tid] = emb[(size_t)(kc * 32 + i) * HD + tid];
    __syncthreads();
#pragma unroll
    for (int c = 0; c < 4; c++) {
      int e = c * 256 + tid;
      int ci = e >> 6, l = e & 63;
      int g = l >> 4, col = ci * 16 + (l & 15);
      uint4 v;
      v.x = pack_bf2(ts[g * 8 + 0][col], ts[g * 8 + 1][col]);
      v.y = pack_bf2(ts[g * 8 + 2][col], ts[g * 8 + 3][col]);
      v.z = pack_bf2(ts[g * 8 + 4][col], ts[g * 8 + 5][col]);
      v.w = pack_bf2(ts[g * 8 + 6][col], ts[g * 8 + 7][col]);
      ((uint4*)Bm)[(size_t)kc * 1024 + e] = v;
    }
  } else {
    const int c = (blockIdx.x - 256) * 256 + tid;   // 0..24575
    const int lcl = c & 63;
    const int ci = (c >> 6) % 24;
    const int kc = c / (24 * 64);
    const int j = ci * 16 + (lcl & 15);
    const int k0 = kc * 32 + ((lcl >> 4) << 3);
    float f[8];
#pragma unroll
    for (int jj = 0; jj < 8; jj++) {
      int k = k0 + jj;
      f[jj] = (j < 128) ? k1[j * 514 + 1 + k]
            : (j < 256) ? k2[(j - 128) * 1028 + 515 + k]
                        : k2[(j - 256) * 1028 + 1 + k];
    }
    uint4 v;
    v.x = pack_bf2(f[0], f[1]); v.y = pack_bf2(f[2], f[3]);
    v.z = pack_bf2(f[4], f[5]); v.w = pack_bf2(f[6], f[7]);
    *(uint4*)(Wm + (size_t)c * 8) = v;
  }
}

// ---------------------------------------------------------------- GEMM:
// BM=64, KSPLIT=8 -> grid 512, 2 blocks/CU. Two 512-k stages, each staged as
// one unthrottled 2KB-per-row burst (r13-verified layout). Stage-1 loads are
// register-held and issued DURING stage-0 compute -> HBM latency hidden under
// MFMA. Barrier-free compute loops; 5 barriers total.
extern "C" __global__ __launch_bounds__(256, 2)
void k_gemm(const float* __restrict__ A, const uint16_t* __restrict__ Bm,
            const int* __restrict__ bx, const int* __restrict__ by,
            uint16_t* __restrict__ Rp) {
  __shared__ __align__(16) uint16_t Asm[64 * 512];   // 64KB; reused as Ct
  const int tid = threadIdx.x;
  const int kblk = blockIdx.x & 7;                   // XCD = bid%8 == kblk
  const int mblk = blockIdx.x >> 3;
  const int wv = tid >> 6, l = tid & 63, g = l >> 4, l15 = l & 15;

  // staging geometry (r13-verified): row r = tid>>2, sub b = tid&3
  const int r = tid >> 2, b = tid & 3;
  const int gr = mblk * 64 + r;
  const int arow = (gr < BATCH) ? bx[gr] : by[gr - BATCH];
  const float* aSrc = A + (size_t)arow * NN + (size_t)kblk * KCH + b * 4;
  const int ris = r >> 4, l15s = r & 15;
  const int joff = (b & 1) << 2;
  const int gb = b >> 1;

#define PACK1(v_, m_) { \
    const int kcp = (m_) >> 1; \
    const int gg = (((m_) & 1) << 1) + gb; \
    const int off = ((kcp * 4 + ris) * 64 + gg * 16 + l15s) * 8 + joff; \
    uint2 u_; u_.x = pack_bf2((v_).x, (v_).y); u_.y = pack_bf2((v_).z, (v_).w); \
    *(uint2*)(Asm + off) = u_; }

  // ---- stage 0: burst load + pack (k 0..511) ----
#pragma unroll
  for (int half = 0; half < 2; ++half) {
    float4 t[16];
#pragma unroll
    for (int m16 = 0; m16 < 16; ++m16)
      t[m16] = *(const float4*)(aSrc + (half * 16 + m16) * 16);
#pragma unroll
    for (int m16 = 0; m16 < 16; ++m16) PACK1(t[m16], half * 16 + m16);
  }
  __syncthreads();                                  // barrier 1

  f32x4 acc[4][4] = {};
  const uint16_t* bWave = Bm + (((size_t)(kblk * 32) * 16 + wv * 4) * 64 + l) * 8;

#define COMPUTE_RANGE(stage, kc0, kc1) \
  _Pragma("unroll") \
  for (int kc = (kc0); kc < (kc1); ++kc) { \
    bf16x8 bfr[4]; \
    _Pragma("unroll") \
    for (int cj = 0; cj < 4; ++cj) \
      bfr[cj] = *(const bf16x8*)(bWave + (((stage) * 16 + kc) * 16 + cj) * 512); \
    _Pragma("unroll") \
    for (int ri = 0; ri < 4; ++ri) { \
      bf16x8 af = *(const bf16x8*)(Asm + (size_t)((kc * 4 + ri) * 64 + l) * 8); \
      _Pragma("unroll") \
      for (int cj = 0; cj < 4; ++cj) \
        acc[ri][cj] = __builtin_amdgcn_mfma_f32_16x16x32_bf16( \
            af, bfr[cj], acc[ri][cj], 0, 0, 0); } }

  // ---- stage-1 prefetch (regs) overlapped with stage-0 compute ----
  float4 s2a[16];
#pragma unroll
  for (int m = 0; m < 16; ++m)
    s2a[m] = *(const float4*)(aSrc + 512 + m * 16);
  COMPUTE_RANGE(0, 0, 8)
  float4 s2b[16];
#pragma unroll
  for (int m = 0; m < 16; ++m)
    s2b[m] = *(const float4*)(aSrc + 512 + (16 + m) * 16);
  COMPUTE_RANGE(0, 8, 16)
  __syncthreads();                                  // barrier 2: LDS reads done
  // ---- pack stage 1 (k 512..1023) ----
#pragma unroll
  for (int m = 0; m < 16; ++m) PACK1(s2a[m], m)
#pragma unroll
  for (int m = 0; m < 16; ++m) PACK1(s2b[m], 16 + m)
  __syncthreads();                                  // barrier 3
  COMPUTE_RANGE(1, 0, 16)
  __syncthreads();                                  // barrier 4: Asm -> Ct

  // ---- epilogue: pack col-pairs, LDS exchange, coalesced stores ----
  uint16_t* Ct = Asm;                               // 64 x 256 bf16 = 32KB
#pragma unroll
  for (int ri = 0; ri < 4; ri++)
#pragma unroll
    for (int cj = 0; cj < 4; cj++)
#pragma unroll
      for (int rr = 0; rr < 4; rr++) {
        float v = acc[ri][cj][rr];
        float vn = __shfl_xor(v, 1);
        if ((l15 & 1) == 0) {
          int row16 = ri * 16 + g * 4 + rr;
          int col = wv * 64 + cj * 16 + l15;
          *(uint32_t*)(Ct + row16 * 256 + col) = pack_bf2(v, vn);
        }
      }
  __syncthreads();                                  // barrier 5
  {
    const int row2 = tid >> 2, cb = (tid & 3) * 64;
    const uint4* src = (const uint4*)(Ct + row2 * 256 + cb);
    uint16_t* dst = Rp + ((size_t)kblk * 4096 + mblk * 64 + row2) * HD + cb;
    uint4 v0 = src[0], v1 = src[1], v2 = src[2], v3 = src[3];
    ((uint4*)dst)[0] = v0; ((uint4*)dst)[1] = v1;
    ((uint4*)dst)[2] = v2; ((uint4*)dst)[3] = v3;
  }
#undef PACK1
#undef COMPUTE_RANGE
}

// ---------------------------------------------------------------- tail:
// 256 blocks x 8 batch rows. Phase 1: reduce 8 Rp partials -> t (bf16 frag
// LDS). Phase 2: MFMA vs Wm. Fused max-pool/score/log-softmax.
extern "C" __global__ __launch_bounds__(256, 2)
void k_tail(const uint16_t* __restrict__ Rp, const uint16_t* __restrict__ Wm,
            const float* __restrict__ b1, const float* __restrict__ b2,
            const float* __restrict__ dw, const float* __restrict__ dbias,
            float* __restrict__ out) {
  __shared__ __align__(16) uint16_t t_frag[16 * 64 * 8];   // 16 KB
  __shared__ float Cl[8][388];
  __shared__ float coef[6][128];
  const int tid = threadIdx.x;
  const int b0 = blockIdx.x * 8;
  const int wv = tid >> 6, l = tid & 63, g = l >> 4, l15 = l & 15;
  if (tid < 128) {
    coef[0][tid] = dw[tid] + dw[256 + tid];
    coef[1][tid] = dw[128 + tid] + dw[384 + tid];
    coef[2][tid] = dw[512 + tid] + dw[768 + tid];
    coef[3][tid] = dw[640 + tid] + dw[896 + tid];
    coef[4][tid] = b1[tid];
    coef[5][tid] = b2[tid];
  }
  {
    const int r = tid >> 5, c8 = (tid & 31) * 8;
    float rq[8] = {}, ra[8] = {};
#pragma unroll
    for (int p = 0; p < KSPLIT; p++) {
      uint4 q4 = *(const uint4*)(Rp + ((size_t)p * 4096 + b0 + r) * HD + c8);
      uint4 a4 = *(const uint4*)(Rp + ((size_t)p * 4096 + BATCH + b0 + r) * HD + c8);
      const uint32_t* qw = (const uint32_t*)&q4;
      const uint32_t* aw = (const uint32_t*)&a4;
#pragma unroll
      for (int w = 0; w < 4; w++) {
        rq[2 * w] += bf_lo(qw[w]); rq[2 * w + 1] += bf_hi(qw[w]);
        ra[2 * w] += bf_lo(aw[w]); ra[2 * w + 1] += bf_hi(aw[w]);
      }
    }
    uint32_t tq[4], ml[4];
#pragma unroll
    for (int w = 0; w < 4; w++) {
      float d0 = rq[2 * w] - ra[2 * w], d1 = rq[2 * w + 1] - ra[2 * w + 1];
      tq[w] = pack_bf2(d0 * d0, d1 * d1);
      ml[w] = pack_bf2(rq[2 * w] * ra[2 * w], rq[2 * w + 1] * ra[2 * w + 1]);
    }
    const int kc1 = c8 >> 5, gm = (c8 >> 3) & 3;
    const int kc2 = 8 + kc1;
    *(uint4*)(t_frag + (kc1 * 64 + gm * 16 + r) * 8) = *(uint4*)tq;
    *(uint4*)(t_frag + (kc2 * 64 + gm * 16 + r) * 8) = *(uint4*)ml;
    uint4 z = {0, 0, 0, 0};
    *(uint4*)(t_frag + (kc1 * 64 + gm * 16 + 8 + r) * 8) = z;
    *(uint4*)(t_frag + (kc2 * 64 + gm * 16 + 8 + r) * 8) = z;
  }
  __syncthreads();
  {
    f32x4 acc[6] = {};
    const uint16_t* wB = Wm + ((size_t)(wv * 6) * 64 + l) * 8;
#pragma unroll 2
    for (int kc = 0; kc < 16; kc++) {
      bf16x8 af = *(const bf16x8*)(t_frag + (kc * 64 + l) * 8);
#pragma unroll
      for (int ci = 0; ci < 6; ci++) {
        bf16x8 w = *(const bf16x8*)(wB + (size_t)kc * 12288 + ci * 512);
        acc[ci] = __builtin_amdgcn_mfma_f32_16x16x32_bf16(af, w, acc[ci], 0, 0, 0);
      }
    }
#pragma unroll
    for (int ci = 0; ci < 6; ci++)
#pragma unroll
      for (int rr = 0; rr < 4; rr++) {
        int row16 = g * 4 + rr;
        if (row16 < 8) Cl[row16][wv * 96 + ci * 16 + l15] = acc[ci][rr];
      }
  }
  __syncthreads();
  {
    const int r = tid >> 5, ch0 = (tid & 31) * 4;
    float s0 = 0.f, s1 = 0.f;
#pragma unroll
    for (int cc = 0; cc < 4; cc++) {
      const int c = ch0 + cc;
      float d1 = Cl[r][c], d2a = Cl[r][128 + c], d2b = Cl[r][256 + c];
      float bb1 = coef[4][c], bb2 = coef[5][c];
      float e1 = fmaxf(0.f, fmaxf(bb1, d1 + bb1));          // max-pool conv1
      float e2 = fmaxf(0.f, fmaxf(d2a + bb2, d2b + bb2));   // max-pool conv2
      s0 += e1 * coef[0][c] + e2 * coef[1][c];
      s1 += e1 * coef[2][c] + e2 * coef[3][c];
    }
#pragma unroll
    for (int off = 16; off >= 1; off >>= 1) {
      s0 += __shfl_xor(s0, off, 32);
      s1 += __shfl_xor(s1, off, 32);
    }
    if ((tid & 31) == 0) {
      s0 += dbias[0]; s1 += dbias[1];
      float m = fmaxf(s0, s1);
      float lse = m + logf(expf(s0 - m) + expf(s1 - m));
      out[(b0 + r) * 2] = s0 - lse;
      out[(b0 + r) * 2 + 1] = s1 - lse;
    }
  }
}

// ---------------------------------------------------------------- launch
extern "C" void kernel_launch(void* const* d_in, const int* in_sizes, int n_in,
                              void* d_out, int out_size, void* d_ws, size_t ws_size,
                              hipStream_t stream) {
  const float* emb = (const float*)d_in[0];
  const float* A   = (const float*)d_in[1];
  const float* k1  = (const float*)d_in[2];
  const float* b1  = (const float*)d_in[3];
  const float* k2  = (const float*)d_in[4];
  const float* b2  = (const float*)d_in[5];
  const float* dw  = (const float*)d_in[6];
  const float* dbi = (const float*)d_in[7];
  const int* bx = (const int*)d_in[8];
  const int* by = (const int*)d_in[9];
  float* out = (float*)d_out;
  char* ws = (char*)d_ws;
  // ws: [0,4M) Bm ; [4M,4.75M) Wm ; [8M,24M) Rp bf16 (KSPLIT=8)
  uint16_t* Bm = (uint16_t*)ws;
  uint16_t* Wm = (uint16_t*)(ws + (4u << 20));
  uint16_t* Rp = (uint16_t*)(ws + (8u << 20));

  k_prep<<<352, 256, 0, stream>>>(emb, k1, k2, Bm, Wm);
  k_gemm<<<64 * KSPLIT, 256, 0, stream>>>(A, Bm, bx, by, Rp);
  k_tail<<<256, 256, 0, stream>>>(Rp, Wm, b1, b2, dw, dbi, out);
}